// Round 1
// baseline (502.585 us; speedup 1.0000x reference)
//
#include <hip/hip_runtime.h>
#include <math.h>

#define B_  32
#define M_  65536
#define W_  32
#define R_  4
#define K_  16
#define C_  65
#define IN_ 256

// ---------------- kernel 1: small matmuls + gather/update -> OVERLAY (inputs read-only) ----
__global__ __launch_bounds__(256) void k_prep(
    const float* __restrict__ xi,
    const float* __restrict__ read_weights, const float* __restrict__ write_weights,
    const float* __restrict__ usage, const float* __restrict__ visible,
    const float* __restrict__ W_rq, const float* __restrict__ b_rq,
    const float* __restrict__ W_wv, const float* __restrict__ b_wv,
    const float* __restrict__ W_ig, const float* __restrict__ b_ig,
    const float* __restrict__ W_wg, const float* __restrict__ b_wg,
    const int* __restrict__ read_pos, const int* __restrict__ timestep_p,
    float* __restrict__ ws_rq, int* __restrict__ upd_row,
    float* __restrict__ upd_usage, float* __restrict__ upd_vals)
{
    const int b = blockIdx.x, t = threadIdx.x;
    __shared__ __align__(16) float s_xi[IN_];
    __shared__ float s_wv[W_];
    __shared__ float s_ig[C_];
    __shared__ float s_wg;
    __shared__ float s_ru[C_], s_rwg[C_], s_u[C_];
    __shared__ float s_I[C_], s_wwnew[C_];
    __shared__ int   s_rp[C_];
    __shared__ float s_minu;

    s_xi[t] = xi[b * IN_ + t];
    __syncthreads();

    if (t < 226) {
        const float* wrow; float bias;
        if (t < 128)      { wrow = W_rq + t * IN_;         bias = b_rq[t]; }
        else if (t < 160) { wrow = W_wv + (t - 128) * IN_; bias = b_wv[t - 128]; }
        else if (t < 225) { wrow = W_ig + (t - 160) * IN_; bias = b_ig[t - 160]; }
        else              { wrow = W_wg;                   bias = b_wg[0]; }
        float acc = 0.f;
        const float4* w4 = (const float4*)wrow;
        const float4* x4 = (const float4*)s_xi;
        #pragma unroll 4
        for (int q = 0; q < IN_ / 4; ++q) {
            float4 wv = w4[q]; float4 xv = x4[q];
            acc = fmaf(wv.x, xv.x, acc); acc = fmaf(wv.y, xv.y, acc);
            acc = fmaf(wv.z, xv.z, acc); acc = fmaf(wv.w, xv.w, acc);
        }
        acc += bias;
        if (t < 128)      ws_rq[b * 128 + t] = acc;
        else if (t < 160) s_wv[t - 128] = acc;
        else if (t < 225) s_ig[t - 160] = 1.f / (1.f + expf(-acc));
        else              s_wg = 1.f / (1.f + expf(-acc));
    }

    const int ts = timestep_p[0];
    if (t < C_) {
        int p = read_pos[b * C_ + t];
        s_rp[t] = p;
        float rwg = read_weights[(size_t)b * M_ + p];
        if (ts == 1) rwg += 1.0f;
        float wwg = write_weights[(size_t)b * M_ + p];
        s_rwg[t] = rwg;
        s_u[t]  = ((rwg + wwg) > 0.005f) ? 1.0f : 0.0f;
        s_ru[t] = usage[(size_t)b * M_ + p];
    }
    __syncthreads();
    if (t == 0) {
        float mn = s_ru[0];
        for (int c = 1; c < C_; ++c) mn = fminf(mn, s_ru[c]);
        s_minu = mn;
    }
    __syncthreads();
    if (t < C_) {
        float ru = s_ru[t];
        float I  = (ru == s_minu) ? 1.0f : 0.0f;
        float u  = s_u[t];
        float relnew = ((float)ts - ru) * u + ru * (1.0f - u);
        float ig = s_ig[t];
        float wwn = s_wg * (ig * s_rwg[t] + (1.0f - ig) * I);
        s_I[t] = I; s_wwnew[t] = wwn;
        upd_usage[b * C_ + t] = relnew;           // duplicate positions share identical relnew
        // last-occurrence-wins duplicate semantics: only the winner keeps its row id
        unsigned char ok = 1;
        for (int c2 = t + 1; c2 < C_; ++c2) if (s_rp[c2] == s_rp[t]) { ok = 0; break; }
        upd_row[b * C_ + t] = ok ? s_rp[t] : -1;
    }
    __syncthreads();
    for (int i = t; i < C_ * W_; i += 256) {
        int c = i >> 5, w = i & 31;
        float v = visible[((size_t)b * C_ + c) * W_ + w] * (1.0f - s_I[c]) + s_wwnew[c] * s_wv[w];
        upd_vals[(size_t)(b * C_ + c) * W_ + w] = v;   // written for all c; losers never read
    }
}

// ---------------- kernel 2: streaming scores (+overlay) + per-lane top-2 + usage-argmin ----
// grid (64, 32), 256 threads; block covers 1024 rows, contiguous.
__global__ __launch_bounds__(256) void k_scores(
    const float* __restrict__ memory, const float* __restrict__ ws_rq,
    const float* __restrict__ usage,
    const int* __restrict__ upd_row, const float* __restrict__ upd_vals,
    float* __restrict__ scores, float* __restrict__ cand,
    float* __restrict__ pval, int* __restrict__ pidx)
{
    const int b = blockIdx.y, x = blockIdx.x, t = threadIdx.x;
    __shared__ float s_rq[128];
    __shared__ __align__(16) float s_sc[4][1032];   // +8 pad: conflict-free scatter
    __shared__ unsigned char s_ovr[1024];           // 0 = original row, else overlay slot+1
    __shared__ float s_oval[C_ * 4];
    __shared__ int   s_novr;
    if (t < 128) s_rq[t] = ws_rq[b * 128 + t];
    for (int i = t; i < 1024; i += 256) s_ovr[i] = 0;
    if (t == 0) s_novr = 0;
    __syncthreads();

    const int rowbase = x << 10;
    // overlay table: rows of this slice that were (virtually) rewritten this step
    if (t < C_) {
        int p = upd_row[b * C_ + t];
        if (p >= rowbase && p < rowbase + 1024) {
            int slot = atomicAdd(&s_novr, 1);
            s_ovr[p - rowbase] = (unsigned char)(slot + 1);
            const float* uv = upd_vals + (size_t)(b * C_ + t) * W_;
            float d0 = 0.f, d1 = 0.f, d2 = 0.f, d3 = 0.f;
            #pragma unroll
            for (int w = 0; w < 32; ++w) {
                float mv = uv[w];
                d0 = fmaf(mv, s_rq[w],      d0);
                d1 = fmaf(mv, s_rq[32 + w], d1);
                d2 = fmaf(mv, s_rq[64 + w], d2);
                d3 = fmaf(mv, s_rq[96 + w], d3);
            }
            s_oval[slot * 4 + 0] = d0; s_oval[slot * 4 + 1] = d1;
            s_oval[slot * 4 + 2] = d2; s_oval[slot * 4 + 3] = d3;
        }
    }
    __syncthreads();

    const int j = t & 7;                 // 8 lanes own one 32-float row
    float q[4][4];
    #pragma unroll
    for (int r = 0; r < 4; ++r)
        #pragma unroll
        for (int k = 0; k < 4; ++k) q[r][k] = s_rq[r * 32 + j * 4 + k];

    const float* src = memory + (size_t)b * (M_ * W_) + (size_t)rowbase * W_;
    const int rloc = t >> 3;             // row within a 32-row chunk

    float m1 = -INFINITY, m2 = -INFINITY;
    #pragma unroll 4
    for (int i = 0; i < 32; ++i) {
        float4 v = *(const float4*)(src + i * 1024 + t * 4);
        float p0 = fmaf(v.w, q[0][3], fmaf(v.z, q[0][2], fmaf(v.y, q[0][1], v.x * q[0][0])));
        float p1 = fmaf(v.w, q[1][3], fmaf(v.z, q[1][2], fmaf(v.y, q[1][1], v.x * q[1][0])));
        float p2 = fmaf(v.w, q[2][3], fmaf(v.z, q[2][2], fmaf(v.y, q[2][1], v.x * q[2][0])));
        float p3 = fmaf(v.w, q[3][3], fmaf(v.z, q[3][2], fmaf(v.y, q[3][1], v.x * q[3][0])));
        #pragma unroll
        for (int m = 1; m <= 4; m <<= 1) {
            p0 += __shfl_xor(p0, m);
            p1 += __shfl_xor(p1, m);
            p2 += __shfl_xor(p2, m);
            p3 += __shfl_xor(p3, m);
        }
        if (j < 4) {
            float wv = (j == 0) ? p0 : (j == 1) ? p1 : (j == 2) ? p2 : p3;
            unsigned char ov = s_ovr[i * 32 + rloc];
            if (ov) wv = s_oval[(ov - 1) * 4 + j];  // overlay BEFORE cand tracking -> tau exact
            s_sc[j][i * 32 + rloc] = wv;
            m2 = fmaxf(m2, fminf(m1, wv)); m1 = fmaxf(m1, wv);
        }
    }
    if (j < 4) {
        float* cd = cand + ((size_t)((b << 2) + j) << 12) + (x << 6) + (rloc << 1);
        cd[0] = m1; cd[1] = m2;
    }
    __syncthreads();
    // coalesced score writes: 4 planes x 4 KB contiguous
    #pragma unroll
    for (int r = 0; r < 4; ++r) {
        float4 v = *(const float4*)&s_sc[r][t * 4];
        *(float4*)(scores + (((size_t)((b << 2) + r)) << 16) + rowbase + t * 4) = v;
    }
    // fused usage-argmin partial; overlaid positions excluded (re-injected in k_final)
    const float* u = usage + (size_t)b * M_ + rowbase;
    float bv = 3.4e38f; int bi = 0x7fffffff;
    #pragma unroll
    for (int i = t; i < 1024; i += 256) {   // per-thread indices ascend -> strict < keeps first
        float v = s_ovr[i] ? 3.5e38f : u[i];
        if (v < bv) { bv = v; bi = i; }
    }
    __syncthreads();                        // s_sc reuse as reduction scratch
    float* sv = s_sc[0]; int* si = (int*)s_sc[1];
    sv[t] = bv; si[t] = bi; __syncthreads();
    for (int s = 128; s > 0; s >>= 1) {
        if (t < s) {
            if (sv[t + s] < sv[t] || (sv[t + s] == sv[t] && si[t + s] < si[t])) {
                sv[t] = sv[t + s]; si[t] = si[t + s];
            }
        }
        __syncthreads();
    }
    if (t == 0) { pval[(b << 6) + x] = sv[0]; pidx[(b << 6) + x] = rowbase + si[0]; }
}

// ---------------- kernel 3: exact top-16 per (b,r): tau from cands -> compact -> select ----
__global__ __launch_bounds__(256) void k_sel(
    const float* __restrict__ scores, const float* __restrict__ cand,
    int* __restrict__ ws_pos)
{
    const int br = blockIdx.x, t = threadIdx.x;
    const float* sc = scores + ((size_t)br << 16);
    const float* cd = cand + ((size_t)br << 12);
    __shared__ float s_cand[512];
    __shared__ float c_val[2048];
    __shared__ int   c_idx[2048];
    __shared__ float s_wv[4]; __shared__ int s_wi[4], s_ws[4];
    __shared__ float s_tau;
    __shared__ int   s_cnt;
    __shared__ int   s_res[16];

    // phase A: per-thread branchless top-2 over the 4096 precomputed candidates
    float m1 = -INFINITY, m2 = -INFINITY;
    #pragma unroll
    for (int i = 0; i < 16; ++i) {
        float v = cd[i * 256 + t];
        m2 = fmaxf(m2, fminf(m1, v)); m1 = fmaxf(m1, v);
    }
    s_cand[t] = m1; s_cand[256 + t] = m2;
    if (t == 0) s_cnt = 0;
    __syncthreads();

    // phase B: tau = exact 16th largest of the 512 candidates (wave 0, shuffle-only).
    if (t < 64) {
        float h[8];
        #pragma unroll
        for (int k = 0; k < 8; ++k) h[k] = s_cand[t * 8 + k];
        float tau = -INFINITY;
        for (int k = 0; k < 16; ++k) {
            float bv = h[0]; int bs = 0;
            #pragma unroll
            for (int q = 1; q < 8; ++q) if (h[q] > bv) { bv = h[q]; bs = q; }
            int bid = t * 8 + bs;
            #pragma unroll
            for (int off = 32; off > 0; off >>= 1) {
                float ov = __shfl_xor(bv, off);
                int   ob = __shfl_xor(bid, off);
                if (ov > bv || (ov == bv && ob < bid)) { bv = ov; bid = ob; }
            }
            #pragma unroll
            for (int q = 0; q < 8; ++q) if (bid == t * 8 + q) h[q] = -INFINITY;
            tau = bv;
        }
        if (t == 0) s_tau = tau;
    }
    __syncthreads();

    // phase C: compact all v >= tau
    const float tau = s_tau;
    #pragma unroll 8
    for (int i = 0; i < 64; ++i) {
        const int base = i * 1024 + t * 4;
        float4 v = *(const float4*)(sc + base);
        if (v.x >= tau) { int p = atomicAdd(&s_cnt, 1); if (p < 2048) { c_val[p] = v.x; c_idx[p] = base; } }
        if (v.y >= tau) { int p = atomicAdd(&s_cnt, 1); if (p < 2048) { c_val[p] = v.y; c_idx[p] = base + 1; } }
        if (v.z >= tau) { int p = atomicAdd(&s_cnt, 1); if (p < 2048) { c_val[p] = v.z; c_idx[p] = base + 2; } }
        if (v.w >= tau) { int p = atomicAdd(&s_cnt, 1); if (p < 2048) { c_val[p] = v.w; c_idx[p] = base + 3; } }
    }
    __syncthreads();
    int n = s_cnt; if (n > 2048) n = 2048;

    // phase D: 16 rounds of block argmax, (val desc, idx asc) tie-break = lax.top_k order
    const int lane = t & 63, wid = t >> 6;
    for (int k = 0; k < 16; ++k) {
        float bv = -INFINITY; int bi = 0x7fffffff, bs = 0;
        for (int p = t; p < n; p += 256) {
            float v = c_val[p]; int id = c_idx[p];
            if (v > bv || (v == bv && id < bi)) { bv = v; bi = id; bs = p; }
        }
        #pragma unroll
        for (int off = 32; off > 0; off >>= 1) {
            float ov = __shfl_xor(bv, off);
            int   oi = __shfl_xor(bi, off);
            int   os = __shfl_xor(bs, off);
            if (ov > bv || (ov == bv && oi < bi)) { bv = ov; bi = oi; bs = os; }
        }
        if (lane == 0) { s_wv[wid] = bv; s_wi[wid] = bi; s_ws[wid] = bs; }
        __syncthreads();
        if (t == 0) {
            float fv = s_wv[0]; int fi = s_wi[0], fs = s_ws[0];
            #pragma unroll
            for (int w2 = 1; w2 < 4; ++w2)
                if (s_wv[w2] > fv || (s_wv[w2] == fv && s_wi[w2] < fi)) { fv = s_wv[w2]; fi = s_wi[w2]; fs = s_ws[w2]; }
            s_res[k] = fi;
            c_val[fs] = -INFINITY;
        }
        __syncthreads();
    }
    if (t < 16) {
        int b = br >> 2, r = br & 3;
        ws_pos[b * C_ + r * 16 + t] = s_res[t];
    }
}

// ---------------- kernel 4: gather (+overlay) + cosine + softmax + weighted sum ----------------
__global__ __launch_bounds__(256) void k_final(
    const float* __restrict__ memory, const float* __restrict__ ws_rq,
    const float* __restrict__ amin_val, const int* __restrict__ amin_idx,
    const int* __restrict__ ws_pos,
    const int* __restrict__ upd_row, const float* __restrict__ upd_vals,
    const float* __restrict__ upd_usage,
    float* __restrict__ out)
{
    const int b = blockIdx.x, t = threadIdx.x;
    __shared__ int   s_pos[C_];
    __shared__ short s_src[C_];
    __shared__ float s_vm[C_ * W_];
    __shared__ float s_rq[128];
    __shared__ float s_vnorm[C_], s_knorm[R_];
    __shared__ float s_a[R_ * C_];
    __shared__ float s_p[R_ * C_];

    if (t < 64) {   // reduce 64 argmin partials, then merge 65 overlay usage candidates
        float bv = amin_val[(b << 6) + t]; int bi = amin_idx[(b << 6) + t];
        #pragma unroll
        for (int off = 32; off > 0; off >>= 1) {
            float ov = __shfl_down(bv, off);
            int   oi = __shfl_down(bi, off);
            if (ov < bv || (ov == bv && oi < bi)) { bv = ov; bi = oi; }
        }
        if (t == 0) {
            for (int c = 0; c < C_; ++c) {
                int p = upd_row[b * C_ + c];
                if (p >= 0) {
                    float v = upd_usage[b * C_ + c];
                    if (v < bv || (v == bv && p < bi)) { bv = v; bi = p; }
                }
            }
            s_pos[64] = bi;
        }
    }
    if (t < 64)  s_pos[t] = ws_pos[b * C_ + t];
    if (t < 128) s_rq[t] = ws_rq[b * 128 + t];
    __syncthreads();

    if (t < C_) {  // clip + overlay source resolution (winner row ids are unique)
        int p = s_pos[t]; p = p < 0 ? 0 : (p > M_ - 1 ? M_ - 1 : p);
        s_pos[t] = p;
        int j = -1;
        for (int c = 0; c < C_; ++c) if (upd_row[b * C_ + c] == p) j = c;
        s_src[t] = (short)j;
    }
    __syncthreads();

    for (int i = t; i < C_ * W_; i += 256) {
        int c = i >> 5, w = i & 31;
        int j = s_src[c];
        s_vm[i] = (j >= 0) ? upd_vals[(size_t)(b * C_ + j) * W_ + w]
                           : memory[((size_t)b * M_ + s_pos[c]) * W_ + w];
    }
    __syncthreads();
    if (t < C_) {
        float s = 0.f;
        for (int w = 0; w < W_; ++w) { float v = s_vm[t * W_ + w]; s = fmaf(v, v, s); }
        s_vnorm[t] = sqrtf(s) + 1e-6f;
    } else if (t < C_ + R_) {
        int r = t - C_;
        float s = 0.f;
        for (int w = 0; w < W_; ++w) { float v = s_rq[r * W_ + w]; s = fmaf(v, v, s); }
        s_knorm[r] = sqrtf(s) + 1e-6f;
    }
    __syncthreads();
    for (int i = t; i < R_ * C_; i += 256) {
        int r = i / C_, c = i % C_;
        float s = 0.f;
        for (int w = 0; w < W_; ++w) s = fmaf(s_vm[c * W_ + w], s_rq[r * W_ + w], s);
        s_a[i] = s / (32.0f * s_vnorm[c] * s_knorm[r] + 1e-6f);
    }
    __syncthreads();
    if (t < R_) {
        float mx = -INFINITY;
        for (int c = 0; c < C_; ++c) mx = fmaxf(mx, s_a[t * C_ + c]);
        float sum = 0.f;
        for (int c = 0; c < C_; ++c) { float e = expf(s_a[t * C_ + c] - mx); s_p[t * C_ + c] = e; sum += e; }
        float inv = 1.f / sum;
        for (int c = 0; c < C_; ++c) s_p[t * C_ + c] *= inv;
    }
    __syncthreads();
    if (t < 128) {
        int r = t >> 5, w = t & 31;
        float s = 0.f;
        for (int c = 0; c < C_; ++c) s = fmaf(s_p[r * C_ + c], s_vm[c * W_ + w], s);
        out[((size_t)b * R_ + r) * W_ + w] = s;
    }
}

extern "C" void kernel_launch(void* const* d_in, const int* in_sizes, int n_in,
                              void* d_out, int out_size, void* d_ws, size_t ws_size,
                              hipStream_t stream)
{
    const float* xi            = (const float*)d_in[0];
    const float* memory        = (const float*)d_in[1];   // READ-ONLY now (writes virtualized)
    const float* read_weights  = (const float*)d_in[2];
    const float* write_weights = (const float*)d_in[3];
    const float* usage         = (const float*)d_in[4];   // READ-ONLY now
    const float* visible       = (const float*)d_in[5];
    const float* W_rq = (const float*)d_in[6];
    const float* b_rq = (const float*)d_in[7];
    const float* W_wv = (const float*)d_in[8];
    const float* b_wv = (const float*)d_in[9];
    const float* W_ig = (const float*)d_in[10];
    const float* b_ig = (const float*)d_in[11];
    const float* W_wg = (const float*)d_in[12];
    const float* b_wg = (const float*)d_in[13];
    const int*   read_pos = (const int*)d_in[14];
    const int*   timestep = (const int*)d_in[16];
    float* out = (float*)d_out;
    (void)in_sizes; (void)n_in; (void)out_size; (void)ws_size;

    // workspace layout (~36 MB); everything read is written earlier in this same launch
    float* ws_rq     = (float*)d_ws;                 // 32*128 = 4096
    float* scores    = ws_rq + 4096;                 // 32*4*65536 floats (32 MB)
    float* cand      = scores + 8388608;             // 32*4*4096 floats (2 MB)
    float* amin_val  = cand + 524288;                // 32*64
    int*   amin_idx  = (int*)(amin_val + 2048);      // 32*64
    int*   ws_pos    = amin_idx + 2048;              // 32*65 (padded to 2112)
    int*   upd_row   = ws_pos + 2112;                // 32*65 (padded to 2112)
    float* upd_usage = (float*)(upd_row + 2112);     // 32*65 (padded to 2112)
    float* upd_vals  = upd_usage + 2112;             // 32*65*32 = 66560

    k_prep<<<dim3(32), dim3(256), 0, stream>>>(xi, read_weights, write_weights,
        usage, visible, W_rq, b_rq, W_wv, b_wv, W_ig, b_ig, W_wg, b_wg,
        read_pos, timestep, ws_rq, upd_row, upd_usage, upd_vals);
    k_scores<<<dim3(64, 32), dim3(256), 0, stream>>>(memory, ws_rq, usage,
        upd_row, upd_vals, scores, cand, amin_val, amin_idx);
    k_sel<<<dim3(128), dim3(256), 0, stream>>>(scores, cand, ws_pos);
    k_final<<<dim3(32), dim3(256), 0, stream>>>(memory, ws_rq, amin_val, amin_idx,
        ws_pos, upd_row, upd_vals, upd_usage, out);
}

// Round 2
// 492.917 us; speedup vs baseline: 1.0196x; 1.0196x over previous
//
#include <hip/hip_runtime.h>
#include <math.h>

#define B_  32
#define M_  65536
#define W_  32
#define R_  4
#define K_  16
#define C_  65
#define IN_ 256

// ---------------- kernel 1: small matmuls + gather/update -> OVERLAY (inputs read-only) ----
__global__ __launch_bounds__(256) void k_prep(
    const float* __restrict__ xi,
    const float* __restrict__ read_weights, const float* __restrict__ write_weights,
    const float* __restrict__ usage, const float* __restrict__ visible,
    const float* __restrict__ W_rq, const float* __restrict__ b_rq,
    const float* __restrict__ W_wv, const float* __restrict__ b_wv,
    const float* __restrict__ W_ig, const float* __restrict__ b_ig,
    const float* __restrict__ W_wg, const float* __restrict__ b_wg,
    const int* __restrict__ read_pos, const int* __restrict__ timestep_p,
    float* __restrict__ ws_rq, int* __restrict__ upd_row,
    float* __restrict__ upd_usage, float* __restrict__ upd_vals)
{
    const int b = blockIdx.x, t = threadIdx.x;
    __shared__ __align__(16) float s_xi[IN_];
    __shared__ float s_wv[W_];
    __shared__ float s_ig[C_];
    __shared__ float s_wg;
    __shared__ float s_ru[C_], s_rwg[C_], s_u[C_];
    __shared__ float s_I[C_], s_wwnew[C_];
    __shared__ int   s_rp[C_];
    __shared__ float s_minu;

    s_xi[t] = xi[b * IN_ + t];
    __syncthreads();

    if (t < 226) {
        const float* wrow; float bias;
        if (t < 128)      { wrow = W_rq + t * IN_;         bias = b_rq[t]; }
        else if (t < 160) { wrow = W_wv + (t - 128) * IN_; bias = b_wv[t - 128]; }
        else if (t < 225) { wrow = W_ig + (t - 160) * IN_; bias = b_ig[t - 160]; }
        else              { wrow = W_wg;                   bias = b_wg[0]; }
        float acc = 0.f;
        const float4* w4 = (const float4*)wrow;
        const float4* x4 = (const float4*)s_xi;
        #pragma unroll 4
        for (int q = 0; q < IN_ / 4; ++q) {
            float4 wv = w4[q]; float4 xv = x4[q];
            acc = fmaf(wv.x, xv.x, acc); acc = fmaf(wv.y, xv.y, acc);
            acc = fmaf(wv.z, xv.z, acc); acc = fmaf(wv.w, xv.w, acc);
        }
        acc += bias;
        if (t < 128)      ws_rq[b * 128 + t] = acc;
        else if (t < 160) s_wv[t - 128] = acc;
        else if (t < 225) s_ig[t - 160] = 1.f / (1.f + expf(-acc));
        else              s_wg = 1.f / (1.f + expf(-acc));
    }

    const int ts = timestep_p[0];
    if (t < C_) {
        int p = read_pos[b * C_ + t];
        s_rp[t] = p;
        float rwg = read_weights[(size_t)b * M_ + p];
        if (ts == 1) rwg += 1.0f;
        float wwg = write_weights[(size_t)b * M_ + p];
        s_rwg[t] = rwg;
        s_u[t]  = ((rwg + wwg) > 0.005f) ? 1.0f : 0.0f;
        s_ru[t] = usage[(size_t)b * M_ + p];
    }
    __syncthreads();
    if (t == 0) {
        float mn = s_ru[0];
        for (int c = 1; c < C_; ++c) mn = fminf(mn, s_ru[c]);
        s_minu = mn;
    }
    __syncthreads();
    if (t < C_) {
        float ru = s_ru[t];
        float I  = (ru == s_minu) ? 1.0f : 0.0f;
        float u  = s_u[t];
        float relnew = ((float)ts - ru) * u + ru * (1.0f - u);
        float ig = s_ig[t];
        float wwn = s_wg * (ig * s_rwg[t] + (1.0f - ig) * I);
        s_I[t] = I; s_wwnew[t] = wwn;
        upd_usage[b * C_ + t] = relnew;           // duplicate positions share identical relnew
        // last-occurrence-wins duplicate semantics: only the winner keeps its row id
        unsigned char ok = 1;
        for (int c2 = t + 1; c2 < C_; ++c2) if (s_rp[c2] == s_rp[t]) { ok = 0; break; }
        upd_row[b * C_ + t] = ok ? s_rp[t] : -1;
    }
    __syncthreads();
    for (int i = t; i < C_ * W_; i += 256) {
        int c = i >> 5, w = i & 31;
        float v = visible[((size_t)b * C_ + c) * W_ + w] * (1.0f - s_I[c]) + s_wwnew[c] * s_wv[w];
        upd_vals[(size_t)(b * C_ + c) * W_ + w] = v;   // written for all c; losers never read
    }
}

// ---------------- kernel 2: streaming scores (+overlay) + IN-BLOCK EXACT TOP-16 + argmin ----
// grid (64, 32), 256 threads; block covers 1024 rows, contiguous.
// Output: blkval/blkidx[(b*4+r)*1024 + x*16 + k] = block-local exact top-16 (lax.top_k order).
__global__ __launch_bounds__(256) void k_scores(
    const float* __restrict__ memory, const float* __restrict__ ws_rq,
    const float* __restrict__ usage,
    const int* __restrict__ upd_row, const float* __restrict__ upd_vals,
    float* __restrict__ blkval, int* __restrict__ blkidx,
    float* __restrict__ pval, int* __restrict__ pidx)
{
    const int b = blockIdx.y, x = blockIdx.x, t = threadIdx.x;
    __shared__ float s_rq[128];
    __shared__ __align__(16) float s_sc[4][1032];   // +8 pad: conflict-free scatter
    __shared__ unsigned char s_ovr[1024];           // 0 = original row, else overlay slot+1
    __shared__ float s_oval[C_ * 4];
    __shared__ int   s_novr;
    if (t < 128) s_rq[t] = ws_rq[b * 128 + t];
    for (int i = t; i < 1024; i += 256) s_ovr[i] = 0;
    if (t == 0) s_novr = 0;
    __syncthreads();

    const int rowbase = x << 10;
    // overlay table: rows of this slice that were (virtually) rewritten this step
    if (t < C_) {
        int p = upd_row[b * C_ + t];
        if (p >= rowbase && p < rowbase + 1024) {
            int slot = atomicAdd(&s_novr, 1);
            s_ovr[p - rowbase] = (unsigned char)(slot + 1);
            const float* uv = upd_vals + (size_t)(b * C_ + t) * W_;
            float d0 = 0.f, d1 = 0.f, d2 = 0.f, d3 = 0.f;
            #pragma unroll
            for (int w = 0; w < 32; ++w) {
                float mv = uv[w];
                d0 = fmaf(mv, s_rq[w],      d0);
                d1 = fmaf(mv, s_rq[32 + w], d1);
                d2 = fmaf(mv, s_rq[64 + w], d2);
                d3 = fmaf(mv, s_rq[96 + w], d3);
            }
            s_oval[slot * 4 + 0] = d0; s_oval[slot * 4 + 1] = d1;
            s_oval[slot * 4 + 2] = d2; s_oval[slot * 4 + 3] = d3;
        }
    }
    __syncthreads();

    const int j = t & 7;                 // 8 lanes own one 32-float row
    float q[4][4];
    #pragma unroll
    for (int r = 0; r < 4; ++r)
        #pragma unroll
        for (int k = 0; k < 4; ++k) q[r][k] = s_rq[r * 32 + j * 4 + k];

    const float* src = memory + (size_t)b * (M_ * W_) + (size_t)rowbase * W_;
    const int rloc = t >> 3;             // row within a 32-row chunk

    #pragma unroll 4
    for (int i = 0; i < 32; ++i) {
        float4 v = *(const float4*)(src + i * 1024 + t * 4);
        float p0 = fmaf(v.w, q[0][3], fmaf(v.z, q[0][2], fmaf(v.y, q[0][1], v.x * q[0][0])));
        float p1 = fmaf(v.w, q[1][3], fmaf(v.z, q[1][2], fmaf(v.y, q[1][1], v.x * q[1][0])));
        float p2 = fmaf(v.w, q[2][3], fmaf(v.z, q[2][2], fmaf(v.y, q[2][1], v.x * q[2][0])));
        float p3 = fmaf(v.w, q[3][3], fmaf(v.z, q[3][2], fmaf(v.y, q[3][1], v.x * q[3][0])));
        #pragma unroll
        for (int m = 1; m <= 4; m <<= 1) {
            p0 += __shfl_xor(p0, m);
            p1 += __shfl_xor(p1, m);
            p2 += __shfl_xor(p2, m);
            p3 += __shfl_xor(p3, m);
        }
        if (j < 4) {
            float wv = (j == 0) ? p0 : (j == 1) ? p1 : (j == 2) ? p2 : p3;
            unsigned char ov = s_ovr[i * 32 + rloc];
            if (ov) wv = s_oval[(ov - 1) * 4 + j];  // overlay substituted before selection
            s_sc[j][i * 32 + rloc] = wv;
        }
    }
    __syncthreads();

    // in-block exact top-16 per r: wave wid handles r=wid; lane owns rows lid+64q (stride-64
    // LDS read = 2 lanes/bank = conflict-free). 16 rounds of argmax with (val desc, row asc)
    // tie-break == lax.top_k order. Exactness: global top-16 is a subset of union of
    // per-block top-16s.
    {
        const int wid = t >> 6, lid = t & 63;
        float h[16];
        #pragma unroll
        for (int qq = 0; qq < 16; ++qq) h[qq] = s_sc[wid][lid + (qq << 6)];
        float resv = 0.f; int resrow = 0;
        for (int k = 0; k < 16; ++k) {
            float bv = h[0]; int br = lid;
            #pragma unroll
            for (int qq = 1; qq < 16; ++qq) {       // rows ascend with qq: strict > keeps first
                int row = lid + (qq << 6);
                if (h[qq] > bv) { bv = h[qq]; br = row; }
            }
            #pragma unroll
            for (int off = 32; off > 0; off >>= 1) {
                float ov = __shfl_xor(bv, off);
                int   orow = __shfl_xor(br, off);
                if (ov > bv || (ov == bv && orow < br)) { bv = ov; br = orow; }
            }
            if (lid == k) { resv = bv; resrow = br; }
            #pragma unroll
            for (int qq = 0; qq < 16; ++qq)          // static-index invalidate (rule #20)
                if (br == lid + (qq << 6)) h[qq] = -INFINITY;
        }
        if (lid < 16) {
            size_t o = (((size_t)((b << 2) + wid)) << 10) + (x << 4) + lid;
            blkval[o] = resv;
            blkidx[o] = rowbase + resrow;
        }
    }

    // fused usage-argmin partial; overlaid positions excluded (re-injected in k_final)
    const float* u = usage + (size_t)b * M_ + rowbase;
    float bv = 3.4e38f; int bi = 0x7fffffff;
    #pragma unroll
    for (int i = t; i < 1024; i += 256) {   // per-thread indices ascend -> strict < keeps first
        float v = s_ovr[i] ? 3.5e38f : u[i];
        if (v < bv) { bv = v; bi = i; }
    }
    __syncthreads();                        // s_sc reuse as reduction scratch
    float* sv = s_sc[0]; int* si = (int*)s_sc[1];
    sv[t] = bv; si[t] = bi; __syncthreads();
    for (int s = 128; s > 0; s >>= 1) {
        if (t < s) {
            if (sv[t + s] < sv[t] || (sv[t + s] == sv[t] && si[t + s] < si[t])) {
                sv[t] = sv[t + s]; si[t] = si[t + s];
            }
        }
        __syncthreads();
    }
    if (t == 0) { pval[(b << 6) + x] = sv[0]; pidx[(b << 6) + x] = rowbase + si[0]; }
}

// ------- kernel 3: merge per-block top-16s -> global top-16, then gather + cosine + softmax ----
__global__ __launch_bounds__(256) void k_final(
    const float* __restrict__ memory, const float* __restrict__ ws_rq,
    const float* __restrict__ amin_val, const int* __restrict__ amin_idx,
    const float* __restrict__ blkval, const int* __restrict__ blkidx,
    const int* __restrict__ upd_row, const float* __restrict__ upd_vals,
    const float* __restrict__ upd_usage,
    float* __restrict__ out)
{
    const int b = blockIdx.x, t = threadIdx.x;
    const int wid = t >> 6, lid = t & 63;
    __shared__ int   s_pos[C_];
    __shared__ short s_src[C_];
    __shared__ float s_vm[C_ * W_];
    __shared__ float s_rq[128];
    __shared__ float s_vnorm[C_], s_knorm[R_];
    __shared__ float s_a[R_ * C_];
    __shared__ float s_p[R_ * C_];

    if (t < 64) {   // reduce 64 argmin partials, then merge 65 overlay usage candidates
        float bv = amin_val[(b << 6) + t]; int bi = amin_idx[(b << 6) + t];
        #pragma unroll
        for (int off = 32; off > 0; off >>= 1) {
            float ov = __shfl_down(bv, off);
            int   oi = __shfl_down(bi, off);
            if (ov < bv || (ov == bv && oi < bi)) { bv = ov; bi = oi; }
        }
        if (t == 0) {
            for (int c = 0; c < C_; ++c) {
                int p = upd_row[b * C_ + c];
                if (p >= 0) {
                    float v = upd_usage[b * C_ + c];
                    if (v < bv || (v == bv && p < bi)) { bv = v; bi = p; }
                }
            }
            s_pos[64] = bi;
        }
    }
    if (t < 128) s_rq[t] = ws_rq[b * 128 + t];

    // global top-16 per r: wave wid merges its 64 blocks x 16 candidates (1024 pairs, L2-hot)
    {
        const size_t base = ((size_t)((b << 2) + wid)) << 10;
        float hv[16]; int hi[16];
        const float4* pv = (const float4*)(blkval + base + lid * 16);
        const int4*   pi = (const int4*)(blkidx + base + lid * 16);
        #pragma unroll
        for (int q4 = 0; q4 < 4; ++q4) {
            float4 v = pv[q4]; int4 ii = pi[q4];
            hv[q4 * 4 + 0] = v.x; hv[q4 * 4 + 1] = v.y; hv[q4 * 4 + 2] = v.z; hv[q4 * 4 + 3] = v.w;
            hi[q4 * 4 + 0] = ii.x; hi[q4 * 4 + 1] = ii.y; hi[q4 * 4 + 2] = ii.z; hi[q4 * 4 + 3] = ii.w;
        }
        int resrow = 0;
        for (int k = 0; k < 16; ++k) {
            float bv = hv[0]; int bi2 = hi[0];
            #pragma unroll
            for (int qq = 1; qq < 16; ++qq)
                if (hv[qq] > bv || (hv[qq] == bv && hi[qq] < bi2)) { bv = hv[qq]; bi2 = hi[qq]; }
            #pragma unroll
            for (int off = 32; off > 0; off >>= 1) {
                float ov = __shfl_xor(bv, off);
                int   oi = __shfl_xor(bi2, off);
                if (ov > bv || (ov == bv && oi < bi2)) { bv = ov; bi2 = oi; }
            }
            if (lid == k) resrow = bi2;
            #pragma unroll
            for (int qq = 0; qq < 16; ++qq)          // global row ids unique -> safe invalidate
                if (hi[qq] == bi2) hv[qq] = -INFINITY;
        }
        if (lid < 16) s_pos[wid * 16 + lid] = resrow;
    }
    __syncthreads();

    if (t < C_) {  // clip + overlay source resolution (winner row ids are unique)
        int p = s_pos[t]; p = p < 0 ? 0 : (p > M_ - 1 ? M_ - 1 : p);
        s_pos[t] = p;
        int j = -1;
        for (int c = 0; c < C_; ++c) if (upd_row[b * C_ + c] == p) j = c;
        s_src[t] = (short)j;
    }
    __syncthreads();

    for (int i = t; i < C_ * W_; i += 256) {
        int c = i >> 5, w = i & 31;
        int j = s_src[c];
        s_vm[i] = (j >= 0) ? upd_vals[(size_t)(b * C_ + j) * W_ + w]
                           : memory[((size_t)b * M_ + s_pos[c]) * W_ + w];
    }
    __syncthreads();
    if (t < C_) {
        float s = 0.f;
        for (int w = 0; w < W_; ++w) { float v = s_vm[t * W_ + w]; s = fmaf(v, v, s); }
        s_vnorm[t] = sqrtf(s) + 1e-6f;
    } else if (t < C_ + R_) {
        int r = t - C_;
        float s = 0.f;
        for (int w = 0; w < W_; ++w) { float v = s_rq[r * W_ + w]; s = fmaf(v, v, s); }
        s_knorm[r] = sqrtf(s) + 1e-6f;
    }
    __syncthreads();
    for (int i = t; i < R_ * C_; i += 256) {
        int r = i / C_, c = i % C_;
        float s = 0.f;
        for (int w = 0; w < W_; ++w) s = fmaf(s_vm[c * W_ + w], s_rq[r * W_ + w], s);
        s_a[i] = s / (32.0f * s_vnorm[c] * s_knorm[r] + 1e-6f);
    }
    __syncthreads();
    if (t < R_) {
        float mx = -INFINITY;
        for (int c = 0; c < C_; ++c) mx = fmaxf(mx, s_a[t * C_ + c]);
        float sum = 0.f;
        for (int c = 0; c < C_; ++c) { float e = expf(s_a[t * C_ + c] - mx); s_p[t * C_ + c] = e; sum += e; }
        float inv = 1.f / sum;
        for (int c = 0; c < C_; ++c) s_p[t * C_ + c] *= inv;
    }
    __syncthreads();
    if (t < 128) {
        int r = t >> 5, w = t & 31;
        float s = 0.f;
        for (int c = 0; c < C_; ++c) s = fmaf(s_p[r * C_ + c], s_vm[c * W_ + w], s);
        out[((size_t)b * R_ + r) * W_ + w] = s;
    }
}

extern "C" void kernel_launch(void* const* d_in, const int* in_sizes, int n_in,
                              void* d_out, int out_size, void* d_ws, size_t ws_size,
                              hipStream_t stream)
{
    const float* xi            = (const float*)d_in[0];
    const float* memory        = (const float*)d_in[1];   // read-only (writes virtualized)
    const float* read_weights  = (const float*)d_in[2];
    const float* write_weights = (const float*)d_in[3];
    const float* usage         = (const float*)d_in[4];   // read-only
    const float* visible       = (const float*)d_in[5];
    const float* W_rq = (const float*)d_in[6];
    const float* b_rq = (const float*)d_in[7];
    const float* W_wv = (const float*)d_in[8];
    const float* b_wv = (const float*)d_in[9];
    const float* W_ig = (const float*)d_in[10];
    const float* b_ig = (const float*)d_in[11];
    const float* W_wg = (const float*)d_in[12];
    const float* b_wg = (const float*)d_in[13];
    const int*   read_pos = (const int*)d_in[14];
    const int*   timestep = (const int*)d_in[16];
    float* out = (float*)d_out;
    (void)in_sizes; (void)n_in; (void)out_size; (void)ws_size;

    // workspace layout (~1.2 MB); everything read is written earlier in this same launch
    float* ws_rq     = (float*)d_ws;                 // 32*128 = 4096
    float* blkval    = ws_rq + 4096;                 // 32*4*64*16 = 131072 floats (512 KB)
    int*   blkidx    = (int*)(blkval + 131072);      // 131072 ints (512 KB)
    float* amin_val  = (float*)(blkidx + 131072);    // 32*64
    int*   amin_idx  = (int*)(amin_val + 2048);      // 32*64
    int*   upd_row   = amin_idx + 2048;              // 32*65 (padded to 2112)
    float* upd_usage = (float*)(upd_row + 2112);     // 32*65 (padded to 2112)
    float* upd_vals  = upd_usage + 2112;             // 32*65*32 = 66560

    k_prep<<<dim3(32), dim3(256), 0, stream>>>(xi, read_weights, write_weights,
        usage, visible, W_rq, b_rq, W_wv, b_wv, W_ig, b_ig, W_wg, b_wg,
        read_pos, timestep, ws_rq, upd_row, upd_usage, upd_vals);
    k_scores<<<dim3(64, 32), dim3(256), 0, stream>>>(memory, ws_rq, usage,
        upd_row, upd_vals, blkval, blkidx, amin_val, amin_idx);
    k_final<<<dim3(32), dim3(256), 0, stream>>>(memory, ws_rq, amin_val, amin_idx,
        blkval, blkidx, upd_row, upd_vals, upd_usage, out);
}